// Round 1
// baseline (227.436 us; speedup 1.0000x reference)
//
#include <hip/hip_runtime.h>
#include <math.h>

// PixelEachSubstitutor fused implementation for MI355X (gfx950).
//
// Structure exploited:
//  (1) Encoder sequence is 9 real rows + 72 all-zero rows. Zero rows share one
//      output row; attention is 9x9 only. mem-projection folds the 72 identical
//      rows via a precomputed column-sum S9.
//  (2) Decoder self-attention input is pixel-independent (broadcast V_feature):
//      y1 and q_ca computed once in a 1-block precompute kernel, which also
//      writes transposed weight copies (coalesced lane-reads in main kernel).
//  Main kernel: 1 wave (64 threads) per pixel, all intermediates in LDS.

__device__ __forceinline__ float gsum32(float v) {
#pragma unroll
  for (int m = 16; m > 0; m >>= 1) v += __shfl_xor(v, m, 32);
  return v;
}

// ---------------------------------------------------------------------------
// Precompute kernel (1 block, 256 threads): transposes + decoder-SA + q_ca.
// ---------------------------------------------------------------------------
__global__ __launch_bounds__(256) void precompute_kernel(
    const float* __restrict__ Vf,          // (10,32)
    const float* __restrict__ dec_sa_in,   // (96,32)
    const float* __restrict__ dec_sa_out,  // (32,32)
    const float* __restrict__ dec_ln1,     // (32)
    const float* __restrict__ dec_ca_in,   // (96,32)
    const float* __restrict__ dec_ca_out,  // (32,32)
    const float* __restrict__ ffV_w,       // (32,81)
    float* __restrict__ y1, float* __restrict__ qca,
    float* __restrict__ ffVT, float* __restrict__ S9,
    float* __restrict__ WkT, float* __restrict__ WvT, float* __restrict__ WoT)
{
  const int tid = threadIdx.x;

  // Transposed weight copies.
  for (int idx = tid; idx < 2592; idx += 256) {  // ffVT[t][j] = ffV_w[j][t]
    int j = idx / 81, t = idx - j * 81;
    ffVT[t * 32 + j] = ffV_w[idx];
  }
  for (int j = tid; j < 32; j += 256) {          // S9[j] = sum_{t=9..80} ffV_w[j][t]
    float s = 0.f;
    for (int t = 9; t < 81; ++t) s += ffV_w[j * 81 + t];
    S9[j] = s;
  }
  for (int idx = tid; idx < 1024; idx += 256) {  // W?T[a][b] = W[b][a]
    int a = idx >> 5, c = idx & 31;
    WkT[idx] = dec_ca_in[(32 + c) * 32 + a];
    WvT[idx] = dec_ca_in[(64 + c) * 32 + a];
    WoT[idx] = dec_ca_out[c * 32 + a];
  }

  // Decoder self-attention on broadcast V_feature (pixel-independent).
  __shared__ float qsa[320], ksa[320], vsa[320], osa[320], zb[320], y1s[320];
  __shared__ float mu[10], rstd[10];

  for (int idx = tid; idx < 960; idx += 256) {
    int m = idx / 320, r = idx - m * 320;
    int t = r >> 5, h = r & 31;
    const float* w = dec_sa_in + (m * 32 + h) * 32;
    const float* yr = Vf + t * 32;
    float s = 0.f;
#pragma unroll
    for (int j = 0; j < 32; ++j) s += yr[j] * w[j];
    (m == 0 ? qsa : m == 1 ? ksa : vsa)[r] = s;
  }
  __syncthreads();

  // nhead=32, head_dim=1, scale=1
  for (int idx = tid; idx < 320; idx += 256) {
    int h = idx & 31;
    float q = qsa[idx];
    float sc[10];
    float mx = -1e30f;
#pragma unroll
    for (int s = 0; s < 10; ++s) { sc[s] = q * ksa[s * 32 + h]; mx = fmaxf(mx, sc[s]); }
    float den = 0.f, acc = 0.f;
#pragma unroll
    for (int s = 0; s < 10; ++s) {
      float e = __expf(sc[s] - mx);
      den += e;
      acc += e * vsa[s * 32 + h];
    }
    osa[idx] = acc / den;
  }
  __syncthreads();

  for (int idx = tid; idx < 320; idx += 256) {   // out-proj + residual
    int t = idx >> 5, c = idx & 31;
    float s = 0.f;
#pragma unroll
    for (int h = 0; h < 32; ++h) s += osa[t * 32 + h] * dec_sa_out[c * 32 + h];
    zb[idx] = Vf[idx] + s;
  }
  __syncthreads();

  if (tid < 10) {                                 // per-row LN stats
    float s1 = 0.f, s2 = 0.f;
    for (int c = 0; c < 32; ++c) { float z = zb[tid * 32 + c]; s1 += z; s2 += z * z; }
    float m = s1 * (1.f / 32.f);
    mu[tid] = m;
    rstd[tid] = 1.0f / sqrtf(s2 * (1.f / 32.f) - m * m + 1e-5f);
  }
  __syncthreads();

  for (int idx = tid; idx < 320; idx += 256) {
    int t = idx >> 5, c = idx & 31;
    float v = (zb[idx] - mu[t]) * rstd[t] * dec_ln1[c];
    y1s[idx] = v;
    y1[idx] = v;
  }
  __syncthreads();

  for (int idx = tid; idx < 320; idx += 256) {    // q_ca = y1 @ Wq_ca.T
    int t = idx >> 5, h = idx & 31;
    const float* w = dec_ca_in + h * 32;
    float s = 0.f;
#pragma unroll
    for (int j = 0; j < 32; ++j) s += y1s[t * 32 + j] * w[j];
    qca[idx] = s;
  }
}

// ---------------------------------------------------------------------------
// Main kernel: one 64-thread block (1 wave) per pixel.
// ---------------------------------------------------------------------------
__global__ __launch_bounds__(64) void pixel_main_kernel(
    const float* __restrict__ x,          // (16,10,30,30)
    const float* __restrict__ enc_in,     // (33,11)
    const float* __restrict__ enc_outw,   // (11,11)
    const float* __restrict__ enc_lin1,   // (11)
    const float* __restrict__ enc_lin2,   // (11)
    const float* __restrict__ enc_ln1,    // (11)
    const float* __restrict__ enc_ln2,    // (11)
    const float* __restrict__ dec_lin1,   // (32)
    const float* __restrict__ dec_lin2,   // (32)
    const float* __restrict__ dec_ln2v,   // (32)
    const float* __restrict__ dec_ln3v,   // (32)
    const float* __restrict__ W_d0,       // (8,32)
    const float* __restrict__ W_d1,       // (8)
    const float* __restrict__ ws_y1, const float* __restrict__ ws_qca,
    const float* __restrict__ ws_ffVT, const float* __restrict__ ws_S9,
    const float* __restrict__ ws_WkT, const float* __restrict__ ws_WvT,
    const float* __restrict__ ws_WoT,
    float* __restrict__ out)
{
  __shared__ float f9[99], q9[99], k9[99], v9[99];
  __shared__ float o9[110];   // 9 real rows + shared row at [99..109]
  __shared__ float fE[110];   // encoder output: 9 real rows + shared row
  __shared__ float memb[352], kca[352], vca[352], oca[320];

  const int b = blockIdx.x;
  const int n = b / 900;
  const int rem = b - n * 900;
  const int pi = rem / 30, pj = rem - (rem / 30) * 30;
  const int lane = threadIdx.x;

  // ---- Step 1: build the 9 real feature rows (t=patch pos, c=channel) ----
  for (int idx = lane; idx < 99; idx += 64) {
    int t = idx / 11, c = idx - t * 11;
    float val = 1.0f;                     // c==10: the ones-channel
    if (c < 10) {
      int di = t / 3, dj = t - (t / 3) * 3;
      int ii = pi + di - 1, jj = pj + dj - 1;
      val = (ii >= 0 && ii < 30 && jj >= 0 && jj < 30)
                ? x[((n * 10 + c) * 30 + ii) * 30 + jj] : 0.0f;
    }
    f9[idx] = val;
  }
  __syncthreads();

  // ---- Step 2: encoder Q,K,V for the 9 real rows ----
  for (int idx = lane; idx < 297; idx += 64) {
    int m = idx / 99, r = idx - m * 99;
    int t = r / 11, i = r - t * 11;
    const float* w = enc_in + (m * 11 + i) * 11;
    const float* fr = f9 + t * 11;
    float s = 0.f;
#pragma unroll
    for (int c = 0; c < 11; ++c) s += fr[c] * w[c];
    (m == 0 ? q9 : m == 1 ? k9 : v9)[r] = s;
  }
  __syncthreads();

  // ---- Step 3: encoder attention (81-seq collapses to 9 + shared row) ----
  if (lane < 9) {
    const int t = lane;
    float qr[11];
#pragma unroll
    for (int i = 0; i < 11; ++i) qr[i] = q9[t * 11 + i];
    float sc[9];
    float mx = 0.0f;  // the 72 zero-score terms participate in the max
#pragma unroll
    for (int s = 0; s < 9; ++s) {
      float d = 0.f;
#pragma unroll
      for (int i = 0; i < 11; ++i) d += qr[i] * k9[s * 11 + i];
      sc[s] = d * 0.3015113445777636f;  // 1/sqrt(11)
      mx = fmaxf(mx, sc[s]);
    }
    float den = 72.0f * __expf(-mx);    // 72 padded keys, score 0, value 0
    float acc[11];
#pragma unroll
    for (int i = 0; i < 11; ++i) acc[i] = 0.f;
#pragma unroll
    for (int s = 0; s < 9; ++s) {
      float e = __expf(sc[s] - mx);
      den += e;
#pragma unroll
      for (int i = 0; i < 11; ++i) acc[i] += e * v9[s * 11 + i];
    }
    float inv = 1.0f / den;
#pragma unroll
    for (int i = 0; i < 11; ++i) o9[t * 11 + i] = acc[i] * inv;
  } else if (lane == 9) {
    // rows t>=9: q=0 -> uniform attention -> o = (sum of 9 real V rows)/81
#pragma unroll
    for (int i = 0; i < 11; ++i) {
      float s = 0.f;
#pragma unroll
      for (int t2 = 0; t2 < 9; ++t2) s += v9[t2 * 11 + i];
      o9[99 + i] = s * (1.0f / 81.0f);
    }
  }
  __syncthreads();

  // ---- Step 4: out-proj + residual + LN1 + FF + LN2 (10 distinct rows) ----
  if (lane < 10) {
    const int t = lane;
    float orow[11], row[11];
#pragma unroll
    for (int i = 0; i < 11; ++i) orow[i] = o9[t * 11 + i];
#pragma unroll
    for (int c = 0; c < 11; ++c) {
      float s = 0.f;
#pragma unroll
      for (int i = 0; i < 11; ++i) s += orow[i] * enc_outw[c * 11 + i];
      row[c] = s + (t < 9 ? f9[t * 11 + c] : 0.0f);  // zero residual for shared row
    }
    // LN * enc_ln1
    {
      float s1 = 0.f;
#pragma unroll
      for (int c = 0; c < 11; ++c) s1 += row[c];
      float mu = s1 * (1.0f / 11.0f);
      float s2 = 0.f;
#pragma unroll
      for (int c = 0; c < 11; ++c) { float d = row[c] - mu; s2 += d * d; }
      float rs = 1.0f / sqrtf(s2 * (1.0f / 11.0f) + 1e-5f);
#pragma unroll
      for (int c = 0; c < 11; ++c) row[c] = (row[c] - mu) * rs * enc_ln1[c];
    }
    // FF: hidden dim 1
    {
      float h = 0.f;
#pragma unroll
      for (int c = 0; c < 11; ++c) h += row[c] * enc_lin1[c];
      h = fmaxf(h, 0.f);
#pragma unroll
      for (int c = 0; c < 11; ++c) row[c] += h * enc_lin2[c];
    }
    // LN * enc_ln2
    {
      float s1 = 0.f;
#pragma unroll
      for (int c = 0; c < 11; ++c) s1 += row[c];
      float mu = s1 * (1.0f / 11.0f);
      float s2 = 0.f;
#pragma unroll
      for (int c = 0; c < 11; ++c) { float d = row[c] - mu; s2 += d * d; }
      float rs = 1.0f / sqrtf(s2 * (1.0f / 11.0f) + 1e-5f);
#pragma unroll
      for (int c = 0; c < 11; ++c) fE[t * 11 + c] = (row[c] - mu) * rs * enc_ln2[c];
    }
  }
  __syncthreads();

  // ---- Step 5: mem[c][j] = sum_{t<9} fE[t][c]*ffVT[t][j] + fE[9][c]*S9[j] ----
  for (int idx = lane; idx < 352; idx += 64) {
    int c = idx >> 5, j = idx & 31;
    float s = fE[99 + c] * ws_S9[j];
#pragma unroll
    for (int t = 0; t < 9; ++t) s += fE[t * 11 + c] * ws_ffVT[t * 32 + j];
    memb[idx] = s;
  }
  __syncthreads();

  // ---- Step 6: cross-attention K,V projections (11x32 each) ----
  for (int idx = lane; idx < 704; idx += 64) {
    int which = idx >= 352;
    int r = which ? idx - 352 : idx;
    int s = r >> 5, h = r & 31;
    const float* WT = which ? ws_WvT : ws_WkT;
    const float* mrow = memb + s * 32;
    float acc = 0.f;
#pragma unroll
    for (int j = 0; j < 32; ++j) acc += mrow[j] * WT[j * 32 + h];
    (which ? vca : kca)[r] = acc;
  }
  __syncthreads();

  // ---- Step 7: cross-attention, 32 heads of dim 1, Lq=10, Lk=11 ----
  for (int idx = lane; idx < 320; idx += 64) {
    int t = idx >> 5, h = idx & 31;
    float q = ws_qca[t * 32 + h];
    float sc[11];
    float mx = -1e30f;
#pragma unroll
    for (int s = 0; s < 11; ++s) { sc[s] = q * kca[s * 32 + h]; mx = fmaxf(mx, sc[s]); }
    float den = 0.f, acc = 0.f;
#pragma unroll
    for (int s = 0; s < 11; ++s) {
      float e = __expf(sc[s] - mx);
      den += e;
      acc += e * vca[s * 32 + h];
    }
    oca[idx] = acc / den;
  }
  __syncthreads();

  // ---- Step 8: out-proj + LN2 + FF + LN3 + head; 32 lanes per row ----
  const int g = lane >> 5;   // group 0/1 -> rows t = 2k+g
  const int c = lane & 31;
#pragma unroll
  for (int k = 0; k < 5; ++k) {
    int t = k * 2 + g;
    float s = 0.f;
#pragma unroll
    for (int h = 0; h < 32; ++h) s += oca[t * 32 + h] * ws_WoT[h * 32 + c];
    float z = ws_y1[t * 32 + c] + s;
    // LN * dec_ln2
    {
      float s1 = gsum32(z), s2 = gsum32(z * z);
      float mu = s1 * (1.0f / 32.0f);
      float var = s2 * (1.0f / 32.0f) - mu * mu;
      z = (z - mu) * (1.0f / sqrtf(var + 1e-5f)) * dec_ln2v[c];
    }
    // FF hidden dim 1
    {
      float d1 = gsum32(z * dec_lin1[c]);
      float h1 = fmaxf(d1, 0.f);
      z = z + h1 * dec_lin2[c];
    }
    // LN * dec_ln3
    {
      float s1 = gsum32(z), s2 = gsum32(z * z);
      float mu = s1 * (1.0f / 32.0f);
      float var = s2 * (1.0f / 32.0f) - mu * mu;
      z = (z - mu) * (1.0f / sqrtf(var + 1e-5f)) * dec_ln3v[c];
    }
    // Head: relu(y @ W_d0.T) @ W_d1.T
    float r = 0.f;
#pragma unroll
    for (int m = 0; m < 8; ++m) {
      float zm = gsum32(z * W_d0[m * 32 + c]);
      r += fmaxf(zm, 0.f) * W_d1[m];
    }
    if (c == 0) out[((n * 10 + t) * 30 + pi) * 30 + pj] = r;
  }
}

// ---------------------------------------------------------------------------
extern "C" void kernel_launch(void* const* d_in, const int* in_sizes, int n_in,
                              void* d_out, int out_size, void* d_ws, size_t ws_size,
                              hipStream_t stream) {
  (void)in_sizes; (void)n_in; (void)out_size; (void)ws_size;
  const float* x          = (const float*)d_in[0];
  const float* Vf         = (const float*)d_in[1];
  const float* enc_in     = (const float*)d_in[2];
  const float* enc_outw   = (const float*)d_in[3];
  const float* enc_lin1   = (const float*)d_in[4];
  const float* enc_lin2   = (const float*)d_in[5];
  const float* enc_ln1    = (const float*)d_in[6];
  const float* enc_ln2    = (const float*)d_in[7];
  const float* ffV_w      = (const float*)d_in[8];
  const float* dec_sa_in  = (const float*)d_in[9];
  const float* dec_sa_out = (const float*)d_in[10];
  const float* dec_ca_in  = (const float*)d_in[11];
  const float* dec_ca_out = (const float*)d_in[12];
  const float* dec_lin1   = (const float*)d_in[13];
  const float* dec_lin2   = (const float*)d_in[14];
  const float* dec_ln1    = (const float*)d_in[15];
  const float* dec_ln2    = (const float*)d_in[16];
  const float* dec_ln3    = (const float*)d_in[17];
  const float* W_d0       = (const float*)d_in[18];
  const float* W_d1       = (const float*)d_in[19];
  float* out = (float*)d_out;

  float* ws   = (float*)d_ws;
  float* y1   = ws;                 // 320
  float* qca  = y1 + 320;           // 320
  float* ffVT = qca + 320;          // 2592
  float* S9   = ffVT + 2592;        // 32
  float* WkT  = S9 + 32;            // 1024
  float* WvT  = WkT + 1024;         // 1024
  float* WoT  = WvT + 1024;         // 1024  (total 6336 floats = 25 KiB)

  hipLaunchKernelGGL(precompute_kernel, dim3(1), dim3(256), 0, stream,
                     Vf, dec_sa_in, dec_sa_out, dec_ln1, dec_ca_in, dec_ca_out,
                     ffV_w, y1, qca, ffVT, S9, WkT, WvT, WoT);

  hipLaunchKernelGGL(pixel_main_kernel, dim3(14400), dim3(64), 0, stream,
                     x, enc_in, enc_outw, enc_lin1, enc_lin2, enc_ln1, enc_ln2,
                     dec_lin1, dec_lin2, dec_ln2, dec_ln3, W_d0, W_d1,
                     y1, qca, ffVT, S9, WkT, WvT, WoT, out);
}

// Round 2
// 202.554 us; speedup vs baseline: 1.1228x; 1.1228x over previous
//
#include <hip/hip_runtime.h>
#include <math.h>

// PixelEachSubstitutor fused implementation for MI355X (gfx950) — round 2.
//
// Algebraic structure exploited (all exact linear-algebra refolds):
//  (1) Encoder seq = 9 real rows + 72 zero rows -> 9x9 attention + 1 shared row.
//  (2) M_enc = Wq^T Wk / sqrt(11): scores computed directly from features.
//  (3) WVO = Wo @ Wv: attention directly emits post-out-proj rows.
//  (4) G_k/G_v = F @ Wk_ca^T / Wv_ca^T with F = ffV rows (+ folded 72-row sum):
//      cross-attn K/V computed straight from encoder output (kills the 11x32x32
//      mem projection, the former dominant phase).
//  (5) Decoder self-attn input is pixel-independent -> y1, qca precomputed once.
// Main kernel: 256 threads = 4 waves/block; each wave = 1 pixel stream
// (2 pixels/wave, grid 1800 -> 14400). All intermediates in per-wave LDS slice.

__device__ __forceinline__ float gsum32(float v) {
#pragma unroll
  for (int m = 16; m > 0; m >>= 1) v += __shfl_xor(v, m, 32);
  return v;
}

// ---------------------------------------------------------------------------
// Precompute kernel (1 block, 256 threads).
// ---------------------------------------------------------------------------
__global__ __launch_bounds__(256) void precompute_kernel(
    const float* __restrict__ Vf,          // (10,32)
    const float* __restrict__ enc_in,      // (33,11)
    const float* __restrict__ enc_outw,    // (11,11)
    const float* __restrict__ ffV_w,       // (32,81)
    const float* __restrict__ dec_sa_in,   // (96,32)
    const float* __restrict__ dec_sa_out,  // (32,32)
    const float* __restrict__ dec_ln1,     // (32)
    const float* __restrict__ dec_ca_in,   // (96,32)
    float* __restrict__ M_enc, float* __restrict__ WVO,
    float* __restrict__ G_k, float* __restrict__ G_v,
    float* __restrict__ y1, float* __restrict__ qca)
{
  const int tid = threadIdx.x;
  const float rs11 = 0.3015113445777636f;  // 1/sqrt(11)

  // M_enc[c][c'] = (Wq^T Wk)[c][c'] / sqrt(11);  WVO[c][c'] = (Wo@Wv)[c][c']
  for (int idx = tid; idx < 121; idx += 256) {
    int c = idx / 11, cp = idx - c * 11;
    float sm = 0.f, sv = 0.f;
    for (int i = 0; i < 11; ++i) {
      sm += enc_in[i * 11 + c] * enc_in[(11 + i) * 11 + cp];
      sv += enc_outw[c * 11 + i] * enc_in[(22 + i) * 11 + cp];
    }
    M_enc[idx] = sm * rs11;
    WVO[idx] = sv;
  }

  // F[t][j]: t<9 -> ffV_w[j][t]; F[9][j] = sum_{t=9..80} ffV_w[j][t]
  __shared__ float Fsh[320];
  for (int idx = tid; idx < 288; idx += 256) {
    int t = idx >> 5, j = idx & 31;
    Fsh[idx] = ffV_w[j * 81 + t];
  }
  if (tid < 32) {
    float s = 0.f;
    for (int t = 9; t < 81; ++t) s += ffV_w[tid * 81 + t];
    Fsh[288 + tid] = s;
  }
  __syncthreads();

  // G_k[t][h] = sum_j F[t][j] * Wk_ca[h][j];  G_v likewise with Wv_ca
  for (int idx = tid; idx < 640; idx += 256) {
    int which = idx >= 320;
    int r = idx - 320 * which;
    int t = r >> 5, h = r & 31;
    const float* w = dec_ca_in + ((which ? 64 : 32) + h) * 32;
    float s = 0.f;
    for (int j = 0; j < 32; ++j) s += Fsh[t * 32 + j] * w[j];
    (which ? G_v : G_k)[r] = s;
  }

  // Decoder self-attention on broadcast V_feature (pixel-independent).
  __shared__ float qsa[320], ksa[320], vsa[320], osa[320], zb[320];
  __shared__ float mu[16], rstd[16];

  for (int idx = tid; idx < 960; idx += 256) {
    int m = idx / 320, r = idx - m * 320;
    int t = r >> 5, h = r & 31;
    const float* w = dec_sa_in + (m * 32 + h) * 32;
    const float* yr = Vf + t * 32;
    float s = 0.f;
#pragma unroll
    for (int j = 0; j < 32; ++j) s += yr[j] * w[j];
    (m == 0 ? qsa : m == 1 ? ksa : vsa)[r] = s;
  }
  __syncthreads();

  for (int idx = tid; idx < 320; idx += 256) {  // nhead=32, hd=1
    int h = idx & 31;
    float q = qsa[idx];
    float sc[10];
    float mx = -1e30f;
#pragma unroll
    for (int s = 0; s < 10; ++s) { sc[s] = q * ksa[s * 32 + h]; mx = fmaxf(mx, sc[s]); }
    float den = 0.f, acc = 0.f;
#pragma unroll
    for (int s = 0; s < 10; ++s) {
      float e = __expf(sc[s] - mx);
      den += e;
      acc += e * vsa[s * 32 + h];
    }
    osa[idx] = acc / den;
  }
  __syncthreads();

  for (int idx = tid; idx < 320; idx += 256) {  // out-proj + residual
    int t = idx >> 5, c = idx & 31;
    float s = 0.f;
#pragma unroll
    for (int h = 0; h < 32; ++h) s += osa[t * 32 + h] * dec_sa_out[c * 32 + h];
    zb[idx] = Vf[idx] + s;
  }
  __syncthreads();

  if (tid < 10) {
    float s1 = 0.f, s2 = 0.f;
    for (int c = 0; c < 32; ++c) { float z = zb[tid * 32 + c]; s1 += z; s2 += z * z; }
    float m = s1 * (1.f / 32.f);
    mu[tid] = m;
    rstd[tid] = 1.f / sqrtf(s2 * (1.f / 32.f) - m * m + 1e-5f);
  }
  __syncthreads();

  for (int idx = tid; idx < 320; idx += 256) {
    int t = idx >> 5, c = idx & 31;
    float v = (zb[idx] - mu[t]) * rstd[t] * dec_ln1[c];
    y1[idx] = v;
    zb[idx] = v;
  }
  __syncthreads();

  for (int idx = tid; idx < 320; idx += 256) {  // qca = y1 @ Wq_ca.T
    int t = idx >> 5, h = idx & 31;
    const float* w = dec_ca_in + h * 32;
    float s = 0.f;
#pragma unroll
    for (int j = 0; j < 32; ++j) s += zb[t * 32 + j] * w[j];
    qca[idx] = s;
  }
}

// ---------------------------------------------------------------------------
// Main kernel: 4 waves/block, each wave processes 2 pixels independently.
// Per-wave LDS slice (floats):
//   F9 0..98 | G 112..210 | VO 224..322 | SC 336..431 (scores, then LN stats)
//   ZR 432..541 | FE 544..653 | KC 656..1007 | VC 1008..1359
//   OC = 0..319 (oca; reuses dead F9/G/VO/SC), ZB = 320..639 (z rows, dead SC/ZR/FE)
// ---------------------------------------------------------------------------
#define SLICE 1376

__global__ __launch_bounds__(256) void pixel_main_kernel(
    const float* __restrict__ x,          // (16,10,30,30)
    const float* __restrict__ M_enc, const float* __restrict__ WVO,
    const float* __restrict__ enc_lin1, const float* __restrict__ enc_lin2,
    const float* __restrict__ enc_ln1, const float* __restrict__ enc_ln2,
    const float* __restrict__ G_k, const float* __restrict__ G_v,
    const float* __restrict__ y1g, const float* __restrict__ qcag,
    const float* __restrict__ dec_ca_out,  // (32,32) used directly as WoT
    const float* __restrict__ dec_lin1, const float* __restrict__ dec_lin2,
    const float* __restrict__ dec_ln2v, const float* __restrict__ dec_ln3v,
    const float* __restrict__ W_d0, const float* __restrict__ W_d1,
    float* __restrict__ out)
{
  __shared__ __align__(16) float sh[4 * SLICE];
  const int wave = threadIdx.x >> 6;
  const int lane = threadIdx.x & 63;
  float* ls = sh + wave * SLICE;
  const int F9 = 0, G = 112, VO = 224, SC = 336, ZR = 432, FE = 544, KC = 656, VC = 1008;
  const int OC = 0, ZB = 320;

  for (int pp = 0; pp < 2; ++pp) {
    const int p = blockIdx.x * 8 + pp * 4 + wave;
    const int n = p / 900;
    const int rem = p - n * 900;
    const int pi = rem / 30, pj = rem - (rem / 30) * 30;

    // P1: build 9 real feature rows f9[t][c]
    for (int idx = lane; idx < 99; idx += 64) {
      int t = idx / 11, c = idx - t * 11;
      float val = 1.0f;
      if (c < 10) {
        int di = t / 3, dj = t - (t / 3) * 3;
        int ii = pi + di - 1, jj = pj + dj - 1;
        val = (ii >= 0 && ii < 30 && jj >= 0 && jj < 30)
                  ? x[((n * 10 + c) * 30 + ii) * 30 + jj] : 0.0f;
      }
      ls[F9 + idx] = val;
    }
    __syncthreads();

    // P2: g = f9 @ M_enc^T (per-row), vo = f9 @ WVO^T  (shared f9 reads)
    for (int idx = lane; idx < 99; idx += 64) {
      int s = idx / 11, c = idx - (idx / 11) * 11;
      const float* Mr = M_enc + c * 11;
      const float* Wr = WVO + c * 11;
      float ag = 0.f, av = 0.f;
#pragma unroll
      for (int cp = 0; cp < 11; ++cp) {
        float fv = ls[F9 + s * 11 + cp];
        ag += Mr[cp] * fv;
        av += Wr[cp] * fv;
      }
      ls[G + idx] = ag;
      ls[VO + idx] = av;
    }
    __syncthreads();

    // P2b: scores sc[t][s] = f9[t] . g[s]   (scale already folded into M_enc)
    for (int idx = lane; idx < 81; idx += 64) {
      int t = idx / 9, s = idx - t * 9;
      float a = 0.f;
#pragma unroll
      for (int c = 0; c < 11; ++c) a += ls[F9 + t * 11 + c] * ls[G + s * 11 + c];
      ls[SC + idx] = a;
    }
    __syncthreads();

    // P3a: row max (padded scores are 0 and participate) -> FE[0..8] scratch
    if (lane < 9) {
      float m = 0.f;
#pragma unroll
      for (int s = 0; s < 9; ++s) m = fmaxf(m, ls[SC + lane * 9 + s]);
      ls[FE + lane] = m;
    }
    __syncthreads();

    // P3b: exponentiate in place
    for (int idx = lane; idx < 81; idx += 64) {
      int t = idx / 9;
      ls[SC + idx] = __expf(ls[SC + idx] - ls[FE + t]);
    }
    __syncthreads();

    // P3c: 1/denominator (72 padded keys contribute 72*exp(-max)) -> FE[16..24]
    if (lane < 9) {
      float den = 72.0f * __expf(-ls[FE + lane]);
#pragma unroll
      for (int s = 0; s < 9; ++s) den += ls[SC + lane * 9 + s];
      ls[FE + 16 + lane] = 1.0f / den;
    }
    __syncthreads();

    // P3d: zrow = attn-out(post-out-proj via vo) + residual; shared row t=9
    for (int idx = lane; idx < 110; idx += 64) {
      int t = idx / 11, c = idx - t * 11;
      float a = 0.f;
      if (t < 9) {
#pragma unroll
        for (int s = 0; s < 9; ++s) a += ls[SC + t * 9 + s] * ls[VO + s * 11 + c];
        a = a * ls[FE + 16 + t] + ls[F9 + idx];
      } else {
#pragma unroll
        for (int s = 0; s < 9; ++s) a += ls[VO + s * 11 + c];
        a *= (1.0f / 81.0f);
      }
      ls[ZR + idx] = a;
    }
    __syncthreads();

    // P4a: LN1 stats -> SC[0..9]=mu, SC[16..25]=rstd
    if (lane < 10) {
      float s1 = 0.f, s2 = 0.f;
#pragma unroll
      for (int c = 0; c < 11; ++c) { float z = ls[ZR + lane * 11 + c]; s1 += z; s2 += z * z; }
      float m = s1 * (1.0f / 11.0f);
      ls[SC + lane] = m;
      ls[SC + 16 + lane] = 1.0f / sqrtf(s2 * (1.0f / 11.0f) - m * m + 1e-5f);
    }
    __syncthreads();

    // P4b: normalize * enc_ln1 in place
    for (int idx = lane; idx < 110; idx += 64) {
      int t = idx / 11, c = idx - t * 11;
      ls[ZR + idx] = (ls[ZR + idx] - ls[SC + t]) * ls[SC + 16 + t] * enc_ln1[c];
    }
    __syncthreads();

    // P4c: FF hidden + LN2 stats -> SC[32..41]=h, SC[48..57]=mu2, SC[64..73]=rstd2
    if (lane < 10) {
      float h = 0.f;
#pragma unroll
      for (int c = 0; c < 11; ++c) h += ls[ZR + lane * 11 + c] * enc_lin1[c];
      h = fmaxf(h, 0.f);
      float s1 = 0.f, s2 = 0.f;
#pragma unroll
      for (int c = 0; c < 11; ++c) {
        float z = ls[ZR + lane * 11 + c] + h * enc_lin2[c];
        s1 += z; s2 += z * z;
      }
      float m = s1 * (1.0f / 11.0f);
      ls[SC + 32 + lane] = h;
      ls[SC + 48 + lane] = m;
      ls[SC + 64 + lane] = 1.0f / sqrtf(s2 * (1.0f / 11.0f) - m * m + 1e-5f);
    }
    __syncthreads();

    // P4d: fE = LN2(z + h*lin2) * enc_ln2
    for (int idx = lane; idx < 110; idx += 64) {
      int t = idx / 11, c = idx - t * 11;
      float z = ls[ZR + idx] + ls[SC + 32 + t] * enc_lin2[c];
      ls[FE + idx] = (z - ls[SC + 48 + t]) * ls[SC + 64 + t] * enc_ln2[c];
    }
    __syncthreads();

    // P5: kca[c][h] = sum_t fE[t][c]*G_k[t][h]; vca likewise (G col in regs)
    {
      const int h = lane & 31, grp = lane >> 5;
      const float* Gb = grp ? G_v : G_k;
      const int dst = grp ? VC : KC;
      float gr[10];
#pragma unroll
      for (int t = 0; t < 10; ++t) gr[t] = Gb[t * 32 + h];
#pragma unroll
      for (int c = 0; c < 11; ++c) {
        float a = 0.f;
#pragma unroll
        for (int t = 0; t < 10; ++t) a += ls[FE + t * 11 + c] * gr[t];
        ls[dst + c * 32 + h] = a;
      }
    }
    __syncthreads();

    // P6: cross-attention (32 heads of dim 1, Lq=10, Lk=11) -> oca @ OC
    for (int it = 0; it < 5; ++it) {
      int idx = it * 64 + lane;
      int t = idx >> 5, h = idx & 31;
      float q = qcag[t * 32 + h];
      float kreg[11];
#pragma unroll
      for (int s = 0; s < 11; ++s) kreg[s] = q * ls[KC + s * 32 + h];
      float mx = kreg[0];
#pragma unroll
      for (int s = 1; s < 11; ++s) mx = fmaxf(mx, kreg[s]);
      float den = 0.f, acc = 0.f;
#pragma unroll
      for (int s = 0; s < 11; ++s) {
        float e = __expf(kreg[s] - mx);
        den += e;
        acc += e * ls[VC + s * 32 + h];
      }
      ls[OC + idx] = acc / den;
    }
    __syncthreads();

    // P7a: out-proj + residual + LN2 + FF + LN3 -> z rows @ ZB
    for (int k = 0; k < 5; ++k) {
      int t = 2 * k + (lane >> 5);
      int c = lane & 31;
      float zacc = 0.f;
      const float4* wrow = (const float4*)(dec_ca_out + c * 32);  // WoT col = row of dec_ca_out
      const float4* orow = (const float4*)(ls + OC + t * 32);
#pragma unroll
      for (int h4 = 0; h4 < 8; ++h4) {
        float4 o4 = orow[h4];
        float4 w4 = wrow[h4];
        zacc += o4.x * w4.x + o4.y * w4.y + o4.z * w4.z + o4.w * w4.w;
      }
      float z = y1g[t * 32 + c] + zacc;
      {
        float s1 = gsum32(z), s2 = gsum32(z * z);
        float mu = s1 * (1.0f / 32.0f);
        z = (z - mu) * (1.0f / sqrtf(s2 * (1.0f / 32.0f) - mu * mu + 1e-5f)) * dec_ln2v[c];
      }
      {
        float d1 = gsum32(z * dec_lin1[c]);
        z += fmaxf(d1, 0.f) * dec_lin2[c];
      }
      {
        float s1 = gsum32(z), s2 = gsum32(z * z);
        float mu = s1 * (1.0f / 32.0f);
        z = (z - mu) * (1.0f / sqrtf(s2 * (1.0f / 32.0f) - mu * mu + 1e-5f)) * dec_ln3v[c];
      }
      ls[ZB + t * 32 + c] = z;
    }
    __syncthreads();

    // P7b: head layer 1: relu(z @ W_d0^T) -> dbuf @ OC[0..79]
    for (int idx = lane; idx < 80; idx += 64) {
      int t = idx >> 3, m = idx & 7;
      const float4* arow = (const float4*)(W_d0 + m * 32);
      const float4* zrow4 = (const float4*)(ls + ZB + t * 32);
      float d = 0.f;
#pragma unroll
      for (int q4 = 0; q4 < 8; ++q4) {
        float4 a4 = arow[q4];
        float4 z4 = zrow4[q4];
        d += a4.x * z4.x + a4.y * z4.y + a4.z * z4.z + a4.w * z4.w;
      }
      ls[OC + idx] = fmaxf(d, 0.f);
    }
    __syncthreads();

    // P7c: head layer 2 + store
    if (lane < 10) {
      float r = 0.f;
#pragma unroll
      for (int m = 0; m < 8; ++m) r += ls[OC + lane * 8 + m] * W_d1[m];
      out[((n * 10 + lane) * 30 + pi) * 30 + pj] = r;
    }
    __syncthreads();
  }
}

// ---------------------------------------------------------------------------
extern "C" void kernel_launch(void* const* d_in, const int* in_sizes, int n_in,
                              void* d_out, int out_size, void* d_ws, size_t ws_size,
                              hipStream_t stream) {
  (void)in_sizes; (void)n_in; (void)out_size; (void)ws_size;
  const float* x          = (const float*)d_in[0];
  const float* Vf         = (const float*)d_in[1];
  const float* enc_in     = (const float*)d_in[2];
  const float* enc_outw   = (const float*)d_in[3];
  const float* enc_lin1   = (const float*)d_in[4];
  const float* enc_lin2   = (const float*)d_in[5];
  const float* enc_ln1    = (const float*)d_in[6];
  const float* enc_ln2    = (const float*)d_in[7];
  const float* ffV_w      = (const float*)d_in[8];
  const float* dec_sa_in  = (const float*)d_in[9];
  const float* dec_sa_out = (const float*)d_in[10];
  const float* dec_ca_in  = (const float*)d_in[11];
  const float* dec_ca_out = (const float*)d_in[12];
  const float* dec_lin1   = (const float*)d_in[13];
  const float* dec_lin2   = (const float*)d_in[14];
  const float* dec_ln1    = (const float*)d_in[15];
  const float* dec_ln2    = (const float*)d_in[16];
  const float* dec_ln3    = (const float*)d_in[17];
  const float* W_d0       = (const float*)d_in[18];
  const float* W_d1       = (const float*)d_in[19];
  float* out = (float*)d_out;

  float* ws    = (float*)d_ws;
  float* M_enc = ws;            // 121 -> pad 128
  float* WVO   = ws + 128;      // 121 -> pad 128
  float* G_k   = ws + 256;      // 320
  float* G_v   = ws + 576;      // 320
  float* y1    = ws + 896;      // 320
  float* qca   = ws + 1216;     // 320   (total 1536 floats = 6 KiB)

  hipLaunchKernelGGL(precompute_kernel, dim3(1), dim3(256), 0, stream,
                     Vf, enc_in, enc_outw, ffV_w, dec_sa_in, dec_sa_out,
                     dec_ln1, dec_ca_in, M_enc, WVO, G_k, G_v, y1, qca);

  hipLaunchKernelGGL(pixel_main_kernel, dim3(1800), dim3(256), 0, stream,
                     x, M_enc, WVO, enc_lin1, enc_lin2, enc_ln1, enc_ln2,
                     G_k, G_v, y1, qca, dec_ca_out, dec_lin1, dec_lin2,
                     dec_ln2, dec_ln3, W_d0, W_d1, out);
}

// Round 3
// 171.542 us; speedup vs baseline: 1.3258x; 1.1808x over previous
//
#include <hip/hip_runtime.h>
#include <math.h>

// PixelEachSubstitutor fused implementation for MI355X (gfx950) — round 3.
//
// Algebraic folds (exact):
//  (1) Encoder seq = 9 real rows + 72 zero rows -> 9x9 attention + 1 shared row.
//  (2) M_enc = Wq^T Wk / sqrt(11): scores direct from features.
//  (3) WVO = Wo @ Wv: attention emits post-out-proj rows directly.
//  (4) G_k/G_v = F @ Wk_ca^T / Wv_ca^T: cross-attn K/V straight from encoder
//      output (mem projection deleted).
//  (5) Decoder self-attn input pixel-independent -> y1, qca precomputed once.
//
// Round-3 structural change: waves are fully independent (1 pixel per wave,
// private LDS slice), so inter-wave __syncthreads() is replaced by a
// wave-local fence (s_waitcnt lgkmcnt(0) + compiler memory barrier). Phases
// merged: softmax and encoder LN/FF pipelines run per-row in registers.

__device__ __forceinline__ float gsum32(float v) {
#pragma unroll
  for (int m = 16; m > 0; m >>= 1) v += __shfl_xor(v, m, 32);
  return v;
}

// Wave-local "syncthreads": orders this wave's LDS writes before its
// subsequent LDS reads. Valid because each wave touches only its own slice.
__device__ __forceinline__ void wsync() {
  asm volatile("s_waitcnt lgkmcnt(0)" ::: "memory");
}

// ---------------------------------------------------------------------------
// Precompute kernel (2 independent blocks, 256 threads each).
//  block 0: M_enc, WVO, G_k, G_v       block 1: decoder-SA chain -> y1, qca
// ---------------------------------------------------------------------------
__global__ __launch_bounds__(256) void precompute_kernel(
    const float* __restrict__ Vf,          // (10,32)
    const float* __restrict__ enc_in,      // (33,11)
    const float* __restrict__ enc_outw,    // (11,11)
    const float* __restrict__ ffV_w,       // (32,81)
    const float* __restrict__ dec_sa_in,   // (96,32)
    const float* __restrict__ dec_sa_out,  // (32,32)
    const float* __restrict__ dec_ln1,     // (32)
    const float* __restrict__ dec_ca_in,   // (96,32)
    float* __restrict__ M_enc, float* __restrict__ WVO,
    float* __restrict__ G_k, float* __restrict__ G_v,
    float* __restrict__ y1, float* __restrict__ qca)
{
  const int tid = threadIdx.x;

  if (blockIdx.x == 0) {
    const float rs11 = 0.3015113445777636f;  // 1/sqrt(11)
    // M_enc[c][c'] = (Wq^T Wk)[c][c']/sqrt(11); WVO[c][c'] = (Wo@Wv)[c][c']
    for (int idx = tid; idx < 121; idx += 256) {
      int c = idx / 11, cp = idx - c * 11;
      float sm = 0.f, sv = 0.f;
      for (int i = 0; i < 11; ++i) {
        sm += enc_in[i * 11 + c] * enc_in[(11 + i) * 11 + cp];
        sv += enc_outw[c * 11 + i] * enc_in[(22 + i) * 11 + cp];
      }
      M_enc[idx] = sm * rs11;
      WVO[idx] = sv;
    }

    // F[t][j]: t<9 -> ffV_w[j][t]; F[9][j] = sum_{t=9..80} ffV_w[j][t]
    __shared__ float Fsh[320];
    for (int idx = tid; idx < 288; idx += 256) {
      int t = idx >> 5, j = idx & 31;
      Fsh[idx] = ffV_w[j * 81 + t];
    }
    if (tid < 32) {
      float s = 0.f;
      for (int t = 9; t < 81; ++t) s += ffV_w[tid * 81 + t];
      Fsh[288 + tid] = s;
    }
    __syncthreads();

    // G_k[t][h] = sum_j F[t][j]*Wk_ca[h][j]; G_v likewise
    for (int idx = tid; idx < 640; idx += 256) {
      int which = idx >= 320;
      int r = idx - 320 * which;
      int t = r >> 5, h = r & 31;
      const float* w = dec_ca_in + ((which ? 64 : 32) + h) * 32;
      float s = 0.f;
      for (int j = 0; j < 32; ++j) s += Fsh[t * 32 + j] * w[j];
      (which ? G_v : G_k)[r] = s;
    }
  } else {
    // Decoder self-attention on broadcast V_feature (pixel-independent).
    __shared__ float qsa[320], ksa[320], vsa[320], osa[320], zb[320];
    __shared__ float mu[16], rstd[16];

    for (int idx = tid; idx < 960; idx += 256) {
      int m = idx / 320, r = idx - m * 320;
      int t = r >> 5, h = r & 31;
      const float* w = dec_sa_in + (m * 32 + h) * 32;
      const float* yr = Vf + t * 32;
      float s = 0.f;
#pragma unroll
      for (int j = 0; j < 32; ++j) s += yr[j] * w[j];
      (m == 0 ? qsa : m == 1 ? ksa : vsa)[r] = s;
    }
    __syncthreads();

    for (int idx = tid; idx < 320; idx += 256) {  // nhead=32, hd=1
      int h = idx & 31;
      float q = qsa[idx];
      float sc[10];
      float mx = -1e30f;
#pragma unroll
      for (int s = 0; s < 10; ++s) { sc[s] = q * ksa[s * 32 + h]; mx = fmaxf(mx, sc[s]); }
      float den = 0.f, acc = 0.f;
#pragma unroll
      for (int s = 0; s < 10; ++s) {
        float e = __expf(sc[s] - mx);
        den += e;
        acc += e * vsa[s * 32 + h];
      }
      osa[idx] = acc / den;
    }
    __syncthreads();

    for (int idx = tid; idx < 320; idx += 256) {  // out-proj + residual
      int t = idx >> 5, c = idx & 31;
      float s = 0.f;
#pragma unroll
      for (int h = 0; h < 32; ++h) s += osa[t * 32 + h] * dec_sa_out[c * 32 + h];
      zb[idx] = Vf[idx] + s;
    }
    __syncthreads();

    if (tid < 10) {
      float s1 = 0.f, s2 = 0.f;
      for (int c = 0; c < 32; ++c) { float z = zb[tid * 32 + c]; s1 += z; s2 += z * z; }
      float m = s1 * (1.f / 32.f);
      mu[tid] = m;
      rstd[tid] = 1.f / sqrtf(s2 * (1.f / 32.f) - m * m + 1e-5f);
    }
    __syncthreads();

    for (int idx = tid; idx < 320; idx += 256) {
      int t = idx >> 5, c = idx & 31;
      float v = (zb[idx] - mu[t]) * rstd[t] * dec_ln1[c];
      y1[idx] = v;
      zb[idx] = v;
    }
    __syncthreads();

    for (int idx = tid; idx < 320; idx += 256) {  // qca = y1 @ Wq_ca.T
      int t = idx >> 5, h = idx & 31;
      const float* w = dec_ca_in + h * 32;
      float s = 0.f;
#pragma unroll
      for (int j = 0; j < 32; ++j) s += zb[t * 32 + j] * w[j];
      qca[idx] = s;
    }
  }
}

// ---------------------------------------------------------------------------
// Main kernel: 4 independent waves/block, 1 pixel per wave, grid 3600.
// Per-wave LDS slice (floats):
//   F9 0..98 | G 112..210 | VO 224..322 | SC 336..431 (scores+invden)
//   ZR 432..541 | FE 544..653 | KC 656..1007 | VC 1008..1359
//   OC = 0..319 (reuses dead F9/G/VO), ZB = 320..639 (dead SC/ZR/FE)
// ---------------------------------------------------------------------------
#define SLICE 1376

__global__ __launch_bounds__(256) void pixel_main_kernel(
    const float* __restrict__ x,          // (16,10,30,30)
    const float* __restrict__ M_enc, const float* __restrict__ WVO,
    const float* __restrict__ enc_lin1, const float* __restrict__ enc_lin2,
    const float* __restrict__ enc_ln1, const float* __restrict__ enc_ln2,
    const float* __restrict__ G_k, const float* __restrict__ G_v,
    const float* __restrict__ y1g, const float* __restrict__ qcag,
    const float* __restrict__ dec_ca_out,  // (32,32): row c = WoT column c
    const float* __restrict__ dec_lin1, const float* __restrict__ dec_lin2,
    const float* __restrict__ dec_ln2v, const float* __restrict__ dec_ln3v,
    const float* __restrict__ W_d0, const float* __restrict__ W_d1,
    float* __restrict__ out)
{
  __shared__ __align__(16) float sh[4 * SLICE];
  const int wave = threadIdx.x >> 6;
  const int lane = threadIdx.x & 63;
  float* ls = sh + wave * SLICE;
  const int F9 = 0, G = 112, VO = 224, SC = 336, ZR = 432, FE = 544, KC = 656, VC = 1008;
  const int OC = 0, ZB = 320;

  const int p = blockIdx.x * 4 + wave;
  const int n = p / 900;
  const int rem = p - n * 900;
  const int pi = rem / 30, pj = rem - (rem / 30) * 30;

  // P1: build 9 real feature rows f9[t][c]
  for (int idx = lane; idx < 99; idx += 64) {
    int t = idx / 11, c = idx - t * 11;
    float val = 1.0f;
    if (c < 10) {
      int di = t / 3, dj = t - (t / 3) * 3;
      int ii = pi + di - 1, jj = pj + dj - 1;
      val = (ii >= 0 && ii < 30 && jj >= 0 && jj < 30)
                ? x[((n * 10 + c) * 30 + ii) * 30 + jj] : 0.0f;
    }
    ls[F9 + idx] = val;
  }
  wsync();

  // P2: g = f9 @ M_enc^T, vo = f9 @ WVO^T
  for (int idx = lane; idx < 99; idx += 64) {
    int s = idx / 11, c = idx - (idx / 11) * 11;
    const float* Mr = M_enc + c * 11;
    const float* Wr = WVO + c * 11;
    float ag = 0.f, av = 0.f;
#pragma unroll
    for (int cp = 0; cp < 11; ++cp) {
      float fv = ls[F9 + s * 11 + cp];
      ag += Mr[cp] * fv;
      av += Wr[cp] * fv;
    }
    ls[G + idx] = ag;
    ls[VO + idx] = av;
  }
  wsync();

  // P2b: scores sc[t][s] = f9[t] . g[s]
  for (int idx = lane; idx < 81; idx += 64) {
    int t = idx / 9, s = idx - (idx / 9) * 9;
    float a = 0.f;
#pragma unroll
    for (int c = 0; c < 11; ++c) a += ls[F9 + t * 11 + c] * ls[G + s * 11 + c];
    ls[SC + idx] = a;
  }
  wsync();

  // P3s: per-row softmax in registers (lanes 0-8); padded keys: 72*exp(-mx)
  if (lane < 9) {
    float e[9];
    float mx = 0.0f;
#pragma unroll
    for (int s = 0; s < 9; ++s) { e[s] = ls[SC + lane * 9 + s]; mx = fmaxf(mx, e[s]); }
    float den = 72.0f * __expf(-mx);
#pragma unroll
    for (int s = 0; s < 9; ++s) {
      e[s] = __expf(e[s] - mx);
      den += e[s];
      ls[SC + lane * 9 + s] = e[s];
    }
    ls[SC + 81 + lane] = 1.0f / den;
  }
  wsync();

  // P3d: zrow = attn-out (via vo) + residual; shared row t=9
  for (int idx = lane; idx < 110; idx += 64) {
    int t = idx / 11, c = idx - (idx / 11) * 11;
    float a = 0.f;
    if (t < 9) {
#pragma unroll
      for (int s = 0; s < 9; ++s) a += ls[SC + t * 9 + s] * ls[VO + s * 11 + c];
      a = a * ls[SC + 81 + t] + ls[F9 + idx];
    } else {
#pragma unroll
      for (int s = 0; s < 9; ++s) a += ls[VO + s * 11 + c];
      a *= (1.0f / 81.0f);
    }
    ls[ZR + idx] = a;
  }
  wsync();

  // P4s: per-row LN1 + FF + LN2 in registers (lanes 0-9) -> FE
  if (lane < 10) {
    float row[11];
#pragma unroll
    for (int c = 0; c < 11; ++c) row[c] = ls[ZR + lane * 11 + c];
    float s1 = 0.f, s2 = 0.f;
#pragma unroll
    for (int c = 0; c < 11; ++c) { s1 += row[c]; s2 += row[c] * row[c]; }
    float mu = s1 * (1.0f / 11.0f);
    float rs = 1.0f / sqrtf(s2 * (1.0f / 11.0f) - mu * mu + 1e-5f);
    float h = 0.f;
#pragma unroll
    for (int c = 0; c < 11; ++c) {
      row[c] = (row[c] - mu) * rs * enc_ln1[c];
      h += row[c] * enc_lin1[c];
    }
    h = fmaxf(h, 0.f);
    float t1 = 0.f, t2 = 0.f;
#pragma unroll
    for (int c = 0; c < 11; ++c) {
      row[c] += h * enc_lin2[c];
      t1 += row[c]; t2 += row[c] * row[c];
    }
    float mu2 = t1 * (1.0f / 11.0f);
    float rs2 = 1.0f / sqrtf(t2 * (1.0f / 11.0f) - mu2 * mu2 + 1e-5f);
#pragma unroll
    for (int c = 0; c < 11; ++c)
      ls[FE + lane * 11 + c] = (row[c] - mu2) * rs2 * enc_ln2[c];
  }
  wsync();

  // P5: kca[c][h] = sum_t fE[t][c]*G_k[t][h]; vca likewise (G col in regs)
  {
    const int h = lane & 31, grp = lane >> 5;
    const float* Gb = grp ? G_v : G_k;
    const int dst = grp ? VC : KC;
    float gr[10];
#pragma unroll
    for (int t = 0; t < 10; ++t) gr[t] = Gb[t * 32 + h];
#pragma unroll
    for (int c = 0; c < 11; ++c) {
      float a = 0.f;
#pragma unroll
      for (int t = 0; t < 10; ++t) a += ls[FE + t * 11 + c] * gr[t];
      ls[dst + c * 32 + h] = a;
    }
  }
  wsync();

  // P6: cross-attention (32 heads of dim 1, Lq=10, Lk=11) -> oca @ OC
  for (int it = 0; it < 5; ++it) {
    int idx = it * 64 + lane;
    int t = idx >> 5, h = idx & 31;
    float q = qcag[t * 32 + h];
    float kreg[11];
#pragma unroll
    for (int s = 0; s < 11; ++s) kreg[s] = q * ls[KC + s * 32 + h];
    float mx = kreg[0];
#pragma unroll
    for (int s = 1; s < 11; ++s) mx = fmaxf(mx, kreg[s]);
    float den = 0.f, acc = 0.f;
#pragma unroll
    for (int s = 0; s < 11; ++s) {
      float e = __expf(kreg[s] - mx);
      den += e;
      acc += e * ls[VC + s * 32 + h];
    }
    ls[OC + idx] = acc / den;
  }
  wsync();

  // P7a: out-proj + residual + LN2 + FF + LN3 -> z rows @ ZB
  for (int k = 0; k < 5; ++k) {
    int t = 2 * k + (lane >> 5);
    int c = lane & 31;
    float zacc = 0.f;
    const float4* wrow = (const float4*)(dec_ca_out + c * 32);
    const float4* orow = (const float4*)(ls + OC + t * 32);
#pragma unroll
    for (int h4 = 0; h4 < 8; ++h4) {
      float4 o4 = orow[h4];
      float4 w4 = wrow[h4];
      zacc += o4.x * w4.x + o4.y * w4.y + o4.z * w4.z + o4.w * w4.w;
    }
    float z = y1g[t * 32 + c] + zacc;
    {
      float s1 = gsum32(z), s2 = gsum32(z * z);
      float mu = s1 * (1.0f / 32.0f);
      z = (z - mu) * (1.0f / sqrtf(s2 * (1.0f / 32.0f) - mu * mu + 1e-5f)) * dec_ln2v[c];
    }
    {
      float d1 = gsum32(z * dec_lin1[c]);
      z += fmaxf(d1, 0.f) * dec_lin2[c];
    }
    {
      float s1 = gsum32(z), s2 = gsum32(z * z);
      float mu = s1 * (1.0f / 32.0f);
      z = (z - mu) * (1.0f / sqrtf(s2 * (1.0f / 32.0f) - mu * mu + 1e-5f)) * dec_ln3v[c];
    }
    ls[ZB + t * 32 + c] = z;
  }
  wsync();

  // P7b: head layer 1: relu(z @ W_d0^T) -> OC[0..79]
  for (int idx = lane; idx < 80; idx += 64) {
    int t = idx >> 3, m = idx & 7;
    const float4* arow = (const float4*)(W_d0 + m * 32);
    const float4* zrow4 = (const float4*)(ls + ZB + t * 32);
    float d = 0.f;
#pragma unroll
    for (int q4 = 0; q4 < 8; ++q4) {
      float4 a4 = arow[q4];
      float4 z4 = zrow4[q4];
      d += a4.x * z4.x + a4.y * z4.y + a4.z * z4.z + a4.w * z4.w;
    }
    ls[OC + idx] = fmaxf(d, 0.f);
  }
  wsync();

  // P7c: head layer 2 + store
  if (lane < 10) {
    float r = 0.f;
#pragma unroll
    for (int m = 0; m < 8; ++m) r += ls[OC + lane * 8 + m] * W_d1[m];
    out[((n * 10 + lane) * 30 + pi) * 30 + pj] = r;
  }
}

// ---------------------------------------------------------------------------
extern "C" void kernel_launch(void* const* d_in, const int* in_sizes, int n_in,
                              void* d_out, int out_size, void* d_ws, size_t ws_size,
                              hipStream_t stream) {
  (void)in_sizes; (void)n_in; (void)out_size; (void)ws_size;
  const float* x          = (const float*)d_in[0];
  const float* Vf         = (const float*)d_in[1];
  const float* enc_in     = (const float*)d_in[2];
  const float* enc_outw   = (const float*)d_in[3];
  const float* enc_lin1   = (const float*)d_in[4];
  const float* enc_lin2   = (const float*)d_in[5];
  const float* enc_ln1    = (const float*)d_in[6];
  const float* enc_ln2    = (const float*)d_in[7];
  const float* ffV_w      = (const float*)d_in[8];
  const float* dec_sa_in  = (const float*)d_in[9];
  const float* dec_sa_out = (const float*)d_in[10];
  const float* dec_ca_in  = (const float*)d_in[11];
  const float* dec_ca_out = (const float*)d_in[12];
  const float* dec_lin1   = (const float*)d_in[13];
  const float* dec_lin2   = (const float*)d_in[14];
  const float* dec_ln1    = (const float*)d_in[15];
  const float* dec_ln2    = (const float*)d_in[16];
  const float* dec_ln3    = (const float*)d_in[17];
  const float* W_d0       = (const float*)d_in[18];
  const float* W_d1       = (const float*)d_in[19];
  float* out = (float*)d_out;

  float* ws    = (float*)d_ws;
  float* M_enc = ws;            // 121 -> pad 128
  float* WVO   = ws + 128;      // 121 -> pad 128
  float* G_k   = ws + 256;      // 320
  float* G_v   = ws + 576;      // 320
  float* y1    = ws + 896;      // 320
  float* qca   = ws + 1216;     // 320   (total 1536 floats = 6 KiB)

  hipLaunchKernelGGL(precompute_kernel, dim3(2), dim3(256), 0, stream,
                     Vf, enc_in, enc_outw, ffV_w, dec_sa_in, dec_sa_out,
                     dec_ln1, dec_ca_in, M_enc, WVO, G_k, G_v, y1, qca);

  hipLaunchKernelGGL(pixel_main_kernel, dim3(3600), dim3(256), 0, stream,
                     x, M_enc, WVO, enc_lin1, enc_lin2, enc_ln1, enc_ln2,
                     G_k, G_v, y1, qca, dec_ca_out, dec_lin1, dec_lin2,
                     dec_ln2, dec_ln3, W_d0, W_d1, out);
}